// Round 2
// baseline (2272.851 us; speedup 1.0000x reference)
//
#include <hip/hip_runtime.h>
#include <stdint.h>

#define DTv 0.2f

// ---------------- threefry2x32, bit-exact to JAX ----------------
__device__ __forceinline__ uint32_t rotl32(uint32_t v, uint32_t r){ return (v<<r)|(v>>(32u-r)); }

__device__ __forceinline__ void tf2x32(uint32_t k0, uint32_t k1, uint32_t& x0, uint32_t& x1){
  const uint32_t k2 = k0 ^ k1 ^ 0x1BD11BDAu;
  x0 += k0; x1 += k1;
#define RND(r) { x0 += x1; x1 = rotl32(x1,(r)); x1 ^= x0; }
  RND(13u) RND(15u) RND(26u) RND(6u)
  x0 += k1; x1 += k2 + 1u;
  RND(17u) RND(29u) RND(16u) RND(24u)
  x0 += k2; x1 += k0 + 2u;
  RND(13u) RND(15u) RND(26u) RND(6u)
  x0 += k0; x1 += k1 + 3u;
  RND(17u) RND(29u) RND(16u) RND(24u)
  x0 += k1; x1 += k2 + 4u;
  RND(13u) RND(15u) RND(26u) RND(6u)
  x0 += k2; x1 += k0 + 5u;
#undef RND
}

__device__ __forceinline__ float u01(uint32_t bits){
  return __uint_as_float((bits >> 9) | 0x3f800000u) - 1.0f;
}

// per-step keys (threefry_partitionable=True semantics):
//   k  = fold_in(key(42), t) = cipher((0,42); (0,t))          -> (c0,c1)
//   ki = split(k,3)[i]       = cipher((c0,c1); (0,i)), BOTH output words
__device__ inline void step_keys(int t, uint32_t* K){
  uint32_t c0 = 0u, c1 = (uint32_t)t;
  tf2x32(0u, 42u, c0, c1);
#pragma unroll
  for (int i = 0; i < 3; ++i){
    uint32_t a = 0u, b = (uint32_t)i;
    tf2x32(c0, c1, a, b);
    K[2*i]   = a;
    K[2*i+1] = b;
  }
}

// ---------------- spike generation ----------------
// partitionable random_bits: per element n, (b1,b2)=cipher(k; (0,n)); bits = b1^b2
__global__ __launch_bounds__(256) void spike_kernel(
    const float* __restrict__ s0, const float* __restrict__ s1, const float* __restrict__ s2,
    float* __restrict__ sp0, float* __restrict__ sp1, float* __restrict__ sp2, int t)
{
  __shared__ uint32_t K[6];
  if (threadIdx.x == 0) step_keys(t, K);
  __syncthreads();
  const int g = blockIdx.x * 256 + threadIdx.x;
  const int N0 = 2560, N1 = 262144;
  const int E0 = N0, E1 = E0 + N1;       // layer extents; total 526848
  const float* s; float* sp; uint32_t kk0, kk1; int n;
  if (g < E0)      { s=s0; sp=sp0; kk0=K[0]; kk1=K[1]; n=g;      }
  else if (g < E1) { s=s1; sp=sp1; kk0=K[2]; kk1=K[3]; n=g-E0;   }
  else             { s=s2; sp=sp2; kk0=K[4]; kk1=K[5]; n=g-E1;   }
  uint32_t x0 = 0u, x1 = (uint32_t)n;
  tf2x32(kk0, kk1, x0, x1);
  const float u = u01(x0 ^ x1);
  const float r = fminf(fmaxf(s[n], 0.f), 1.f);
  sp[n] = (u < r) ? 1.0f : 0.0f;
}

// ---------------- init / final copies ----------------
__global__ __launch_bounds__(256) void init_kernel(
    const float* __restrict__ s0i, const float* __restrict__ s1i, const float* __restrict__ s2i,
    const float* __restrict__ data,
    float* __restrict__ b0s, float* __restrict__ b1s, float* __restrict__ b2s,
    float* __restrict__ out_data)
{
  const int i = blockIdx.x*256 + threadIdx.x;
  if (i < 2560)   b0s[i] = s0i[i];
  if (i < 262144){ b1s[i] = s1i[i]; b2s[i] = s2i[i]; }
  if (i < 200704) out_data[i] = data[i];
}

__global__ __launch_bounds__(256) void final_kernel(
    const float* __restrict__ b0s, const float* __restrict__ b1s, const float* __restrict__ b2s,
    float* __restrict__ out)
{
  const int i = blockIdx.x*256 + threadIdx.x;
  if (i < 2560)   out[i] = b0s[i];
  if (i < 262144){ out[2560+i] = b1s[i]; out[264704+i] = b2s[i]; }
}

// ---------------- D2 = data @ W4^T + b4  (256x1024, K=784) ----------------
__global__ __launch_bounds__(256) void d2_kernel(
    const float* __restrict__ data, const float* __restrict__ W4,
    const float* __restrict__ b4, float* __restrict__ D2)
{
  __shared__ float As[16][64];
  __shared__ float Bs[16][64];
  const int R0 = (blockIdx.x >> 4) << 6;
  const int C0 = (blockIdx.x & 15) << 6;
  const int tid = threadIdx.x;
  const int ty = tid >> 4, tx = tid & 15;
  const int mA = tid >> 2, kqA = (tid & 3) << 2;
  float acc[4][4] = {{0.f}};
  for (int kk = 0; kk < 784; kk += 16){
    const float4 a = *(const float4*)&data[(R0+mA)*784 + kk + kqA];
    As[kqA+0][mA]=a.x; As[kqA+1][mA]=a.y; As[kqA+2][mA]=a.z; As[kqA+3][mA]=a.w;
    const float4 b = *(const float4*)&W4[(C0+mA)*784 + kk + kqA];   // Bs[k][c] = W4[c][k]
    Bs[kqA+0][mA]=b.x; Bs[kqA+1][mA]=b.y; Bs[kqA+2][mA]=b.z; Bs[kqA+3][mA]=b.w;
    __syncthreads();
#pragma unroll
    for (int k=0;k<16;k++){
      const float4 av = *(const float4*)&As[k][ty<<2];
      const float4 bv = *(const float4*)&Bs[k][tx<<2];
      acc[0][0]=fmaf(av.x,bv.x,acc[0][0]); acc[0][1]=fmaf(av.x,bv.y,acc[0][1]);
      acc[0][2]=fmaf(av.x,bv.z,acc[0][2]); acc[0][3]=fmaf(av.x,bv.w,acc[0][3]);
      acc[1][0]=fmaf(av.y,bv.x,acc[1][0]); acc[1][1]=fmaf(av.y,bv.y,acc[1][1]);
      acc[1][2]=fmaf(av.y,bv.z,acc[1][2]); acc[1][3]=fmaf(av.y,bv.w,acc[1][3]);
      acc[2][0]=fmaf(av.z,bv.x,acc[2][0]); acc[2][1]=fmaf(av.z,bv.y,acc[2][1]);
      acc[2][2]=fmaf(av.z,bv.z,acc[2][2]); acc[2][3]=fmaf(av.z,bv.w,acc[2][3]);
      acc[3][0]=fmaf(av.w,bv.x,acc[3][0]); acc[3][1]=fmaf(av.w,bv.y,acc[3][1]);
      acc[3][2]=fmaf(av.w,bv.z,acc[3][2]); acc[3][3]=fmaf(av.w,bv.w,acc[3][3]);
    }
    __syncthreads();
  }
#pragma unroll
  for (int i=0;i<4;i++){
    const int r = R0 + (ty<<2) + i;
    float4 o; float* op=(float*)&o;
#pragma unroll
    for (int j=0;j<4;j++){
      const int c = C0 + (tx<<2) + j;
      op[j] = acc[i][j] + b4[c];
    }
    *(float4*)&D2[r*1024 + C0 + (tx<<2)] = o;
  }
}

// ---------------- per-step fused update ----------------
// blocks 0..63   : s1 tiles  (sp2 @ W3 row-major  + epilogue sp0@W1^T + b2)
// blocks 64..127 : s2 tiles  (rho(s1) @ W2 row-major + epilogue D2)
// blocks 128..143: s0 rows   (sp1 @ W0^T via W1, K=1024, 16 rows/block)
__global__ __launch_bounds__(256) void update_kernel(
    const float* __restrict__ s0o, const float* __restrict__ s1o, const float* __restrict__ s2o,
    const float* __restrict__ sp0, const float* __restrict__ sp1, const float* __restrict__ sp2,
    const float* __restrict__ W1, const float* __restrict__ W2, const float* __restrict__ b2,
    const float* __restrict__ W3, const float* __restrict__ b0, const float* __restrict__ D2,
    float* __restrict__ s0n, float* __restrict__ s1n, float* __restrict__ s2n)
{
  const int bid = blockIdx.x;
  const int tid = threadIdx.x;
  if (bid < 128){
    __shared__ float As[16][64];
    __shared__ float Bs[16][64];
    const bool m1 = bid < 64;
    const int tb = m1 ? bid : bid - 64;
    const int R0 = (tb >> 4) << 6;
    const int C0 = (tb & 15) << 6;
    const float* __restrict__ A = m1 ? sp2 : s1o;
    const float* __restrict__ B = m1 ? W3  : W2;
    const int ty = tid >> 4, tx = tid & 15;
    const int mA = tid >> 2, kqA = (tid & 3) << 2;
    const int kB = tid >> 4, cB = (tid & 15) << 2;
    float acc[4][4] = {{0.f}};
    for (int kk = 0; kk < 1024; kk += 16){
      float4 a = *(const float4*)&A[(R0+mA)*1024 + kk + kqA];
      if (!m1){   // A = rho(s1)
        a.x = fminf(fmaxf(a.x,0.f),1.f); a.y = fminf(fmaxf(a.y,0.f),1.f);
        a.z = fminf(fmaxf(a.z,0.f),1.f); a.w = fminf(fmaxf(a.w,0.f),1.f);
      }
      As[kqA+0][mA]=a.x; As[kqA+1][mA]=a.y; As[kqA+2][mA]=a.z; As[kqA+3][mA]=a.w;
      *(float4*)&Bs[kB][cB] = *(const float4*)&B[(kk+kB)*1024 + C0 + cB];
      __syncthreads();
#pragma unroll
      for (int k=0;k<16;k++){
        const float4 av = *(const float4*)&As[k][ty<<2];
        const float4 bv = *(const float4*)&Bs[k][tx<<2];
        acc[0][0]=fmaf(av.x,bv.x,acc[0][0]); acc[0][1]=fmaf(av.x,bv.y,acc[0][1]);
        acc[0][2]=fmaf(av.x,bv.z,acc[0][2]); acc[0][3]=fmaf(av.x,bv.w,acc[0][3]);
        acc[1][0]=fmaf(av.y,bv.x,acc[1][0]); acc[1][1]=fmaf(av.y,bv.y,acc[1][1]);
        acc[1][2]=fmaf(av.y,bv.z,acc[1][2]); acc[1][3]=fmaf(av.y,bv.w,acc[1][3]);
        acc[2][0]=fmaf(av.z,bv.x,acc[2][0]); acc[2][1]=fmaf(av.z,bv.y,acc[2][1]);
        acc[2][2]=fmaf(av.z,bv.z,acc[2][2]); acc[2][3]=fmaf(av.z,bv.w,acc[2][3]);
        acc[3][0]=fmaf(av.w,bv.x,acc[3][0]); acc[3][1]=fmaf(av.w,bv.y,acc[3][1]);
        acc[3][2]=fmaf(av.w,bv.z,acc[3][2]); acc[3][3]=fmaf(av.w,bv.w,acc[3][3]);
      }
      __syncthreads();
    }
    if (m1){
#pragma unroll
      for (int i=0;i<4;i++){
        const int r = R0 + (ty<<2) + i;
        float sv[10];
#pragma unroll
        for (int k=0;k<10;k++) sv[k] = sp0[r*10+k];
        float4 o; float* op=(float*)&o;
#pragma unroll
        for (int j=0;j<4;j++){
          const int c = C0 + (tx<<2) + j;
          float sm = 0.f;
#pragma unroll
          for (int k=0;k<10;k++) sm = fmaf(sv[k], W1[c*10+k], sm);   // sp0 @ W1^T
          const float s = s1o[r*1024+c];
          float v = s + DTv*(-s + acc[i][j] + b2[c] + sm);
          op[j] = fminf(fmaxf(v,0.f),1.f);
        }
        *(float4*)&s1n[r*1024 + C0 + (tx<<2)] = o;
      }
    } else {
#pragma unroll
      for (int i=0;i<4;i++){
        const int r = R0 + (ty<<2) + i;
        float4 o; float* op=(float*)&o;
#pragma unroll
        for (int j=0;j<4;j++){
          const int c = C0 + (tx<<2) + j;
          const float s = s2o[r*1024+c];
          float v = s + DTv*(-s + acc[i][j] + D2[r*1024+c]);
          op[j] = fminf(fmaxf(v,0.f),1.f);
        }
        *(float4*)&s2n[r*1024 + C0 + (tx<<2)] = o;
      }
    }
  } else {
    // s0: 16 rows per block, 16 lanes per row
    const int r    = ((bid - 128) << 4) + (tid >> 4);
    const int lane = tid & 15;
    float a[10] = {0.f,0.f,0.f,0.f,0.f,0.f,0.f,0.f,0.f,0.f};
    for (int k = lane; k < 1024; k += 16){
      const float sv = sp1[r*1024 + k];
#pragma unroll
      for (int c=0;c<10;c++) a[c] = fmaf(sv, W1[k*10+c], a[c]);   // W1[k][c] = W0[c][k]
    }
#pragma unroll
    for (int c=0;c<10;c++){
      float v = a[c];
      v += __shfl_xor(v, 1);
      v += __shfl_xor(v, 2);
      v += __shfl_xor(v, 4);
      v += __shfl_xor(v, 8);
      a[c] = v;
    }
    if (lane == 0){
#pragma unroll
      for (int c=0;c<10;c++){
        const float s = s0o[r*10+c];
        float v = s + DTv*(-s + a[c] + b0[c]);
        s0n[r*10+c] = fminf(fmaxf(v,0.f),1.f);
      }
    }
  }
}

// ---------------- host ----------------
extern "C" void kernel_launch(void* const* d_in, const int* in_sizes, int n_in,
                              void* d_out, int out_size, void* d_ws, size_t ws_size,
                              hipStream_t stream)
{
  const float* data = (const float*)d_in[0];
  const float* s0i  = (const float*)d_in[1];
  const float* s1i  = (const float*)d_in[2];
  const float* s2i  = (const float*)d_in[3];
  const float* b0   = (const float*)d_in[5];
  const float* W1   = (const float*)d_in[6];
  const float* W2   = (const float*)d_in[7];
  const float* b2   = (const float*)d_in[8];
  const float* W3   = (const float*)d_in[9];
  const float* W4   = (const float*)d_in[10];
  const float* b4   = (const float*)d_in[11];
  float* out = (float*)d_out;
  float* ws  = (float*)d_ws;

  // ws layout (floats): two state buffers + spikes + D2  (~7.4 MB total)
  float* S[2][3];
  S[0][0]=ws;             S[0][1]=ws+2560;          S[0][2]=ws+2560+262144;
  float* base1 = ws + 526848;
  S[1][0]=base1;          S[1][1]=base1+2560;       S[1][2]=base1+2560+262144;
  float* sp0 = ws + 1053696;
  float* sp1 = sp0 + 2560;
  float* sp2 = sp1 + 262144;
  float* D2  = sp2 + 262144;

  init_kernel<<<1024,256,0,stream>>>(s0i,s1i,s2i,data, S[0][0],S[0][1],S[0][2], out + 526848);
  d2_kernel<<<64,256,0,stream>>>(data, W4, b4, D2);
  int cur = 0;
  for (int t = 0; t < 30; ++t){
    spike_kernel<<<2058,256,0,stream>>>(S[cur][0],S[cur][1],S[cur][2], sp0,sp1,sp2, t);
    update_kernel<<<144,256,0,stream>>>(S[cur][0],S[cur][1],S[cur][2], sp0,sp1,sp2,
                                        W1,W2,b2,W3,b0,D2,
                                        S[cur^1][0],S[cur^1][1],S[cur^1][2]);
    cur ^= 1;
  }
  final_kernel<<<1024,256,0,stream>>>(S[cur][0],S[cur][1],S[cur][2], out);
}

// Round 3
// 1166.213 us; speedup vs baseline: 1.9489x; 1.9489x over previous
//
#include <hip/hip_runtime.h>
#include <stdint.h>

#define DTv 0.2f

// ---------------- threefry2x32, bit-exact to JAX (partitionable) ----------------
__device__ __forceinline__ uint32_t rotl32(uint32_t v, uint32_t r){ return (v<<r)|(v>>(32u-r)); }

__device__ __forceinline__ void tf2x32(uint32_t k0, uint32_t k1, uint32_t& x0, uint32_t& x1){
  const uint32_t k2 = k0 ^ k1 ^ 0x1BD11BDAu;
  x0 += k0; x1 += k1;
#define RND(r) { x0 += x1; x1 = rotl32(x1,(r)); x1 ^= x0; }
  RND(13u) RND(15u) RND(26u) RND(6u)
  x0 += k1; x1 += k2 + 1u;
  RND(17u) RND(29u) RND(16u) RND(24u)
  x0 += k2; x1 += k0 + 2u;
  RND(13u) RND(15u) RND(26u) RND(6u)
  x0 += k0; x1 += k1 + 3u;
  RND(17u) RND(29u) RND(16u) RND(24u)
  x0 += k1; x1 += k2 + 4u;
  RND(13u) RND(15u) RND(26u) RND(6u)
  x0 += k2; x1 += k0 + 5u;
#undef RND
}

__device__ __forceinline__ float u01(uint32_t bits){
  return __uint_as_float((bits >> 9) | 0x3f800000u) - 1.0f;
}

// k = fold_in(key(42), t) = cipher((0,42);(0,t)); ki = split(k,3)[i] = cipher(k;(0,i))
__device__ inline void step_keys(int t, uint32_t* K){
  uint32_t c0 = 0u, c1 = (uint32_t)t;
  tf2x32(0u, 42u, c0, c1);
#pragma unroll
  for (int i = 0; i < 3; ++i){
    uint32_t a = 0u, b = (uint32_t)i;
    tf2x32(c0, c1, a, b);
    K[2*i] = a; K[2*i+1] = b;
  }
}

// ---------------- spike generation for t=0 only ----------------
__global__ __launch_bounds__(256) void spike_kernel(
    const float* __restrict__ s0, const float* __restrict__ s1, const float* __restrict__ s2,
    float* __restrict__ sp0, float* __restrict__ sp1, float* __restrict__ sp2, int t)
{
  __shared__ uint32_t K[6];
  if (threadIdx.x == 0) step_keys(t, K);
  __syncthreads();
  const int g = blockIdx.x * 256 + threadIdx.x;
  const int E0 = 2560, E1 = E0 + 262144;
  const float* s; float* sp; uint32_t kk0, kk1; int n;
  if (g < E0)      { s=s0; sp=sp0; kk0=K[0]; kk1=K[1]; n=g;      }
  else if (g < E1) { s=s1; sp=sp1; kk0=K[2]; kk1=K[3]; n=g-E0;   }
  else             { s=s2; sp=sp2; kk0=K[4]; kk1=K[5]; n=g-E1;   }
  uint32_t x0 = 0u, x1 = (uint32_t)n;
  tf2x32(kk0, kk1, x0, x1);
  const float u = u01(x0 ^ x1);
  const float r = fminf(fmaxf(s[n], 0.f), 1.f);
  sp[n] = (u < r) ? 1.0f : 0.0f;
}

// ---------------- init / final copies ----------------
__global__ __launch_bounds__(256) void init_kernel(
    const float* __restrict__ s0i, const float* __restrict__ s1i, const float* __restrict__ s2i,
    const float* __restrict__ data,
    float* __restrict__ b0s, float* __restrict__ b1s, float* __restrict__ b2s,
    float* __restrict__ out_data)
{
  const int i = blockIdx.x*256 + threadIdx.x;
  if (i < 2560)   b0s[i] = s0i[i];
  if (i < 262144){ b1s[i] = s1i[i]; b2s[i] = s2i[i]; }
  if (i < 200704) out_data[i] = data[i];
}

__global__ __launch_bounds__(256) void final_kernel(
    const float* __restrict__ b0s, const float* __restrict__ b1s, const float* __restrict__ b2s,
    float* __restrict__ out)
{
  const int i = blockIdx.x*256 + threadIdx.x;
  if (i < 2560)   out[i] = b0s[i];
  if (i < 262144){ out[2560+i] = b1s[i]; out[264704+i] = b2s[i]; }
}

// ---------------- D2 = data @ W4^T + b4  (256x1024, K=784) ----------------
__global__ __launch_bounds__(256) void d2_kernel(
    const float* __restrict__ data, const float* __restrict__ W4,
    const float* __restrict__ b4, float* __restrict__ D2)
{
  __shared__ float As[16][64];
  __shared__ float Bs[16][64];
  const int R0 = (blockIdx.x >> 4) << 6;
  const int C0 = (blockIdx.x & 15) << 6;
  const int tid = threadIdx.x;
  const int ty = tid >> 4, tx = tid & 15;
  const int mA = tid >> 2, kqA = (tid & 3) << 2;
  float acc[4][4] = {{0.f}};
  for (int kk = 0; kk < 784; kk += 16){
    const float4 a = *(const float4*)&data[(R0+mA)*784 + kk + kqA];
    As[kqA+0][mA]=a.x; As[kqA+1][mA]=a.y; As[kqA+2][mA]=a.z; As[kqA+3][mA]=a.w;
    const float4 b = *(const float4*)&W4[(C0+mA)*784 + kk + kqA];
    Bs[kqA+0][mA]=b.x; Bs[kqA+1][mA]=b.y; Bs[kqA+2][mA]=b.z; Bs[kqA+3][mA]=b.w;
    __syncthreads();
#pragma unroll
    for (int k=0;k<16;k++){
      const float4 av = *(const float4*)&As[k][ty<<2];
      const float4 bv = *(const float4*)&Bs[k][tx<<2];
      acc[0][0]=fmaf(av.x,bv.x,acc[0][0]); acc[0][1]=fmaf(av.x,bv.y,acc[0][1]);
      acc[0][2]=fmaf(av.x,bv.z,acc[0][2]); acc[0][3]=fmaf(av.x,bv.w,acc[0][3]);
      acc[1][0]=fmaf(av.y,bv.x,acc[1][0]); acc[1][1]=fmaf(av.y,bv.y,acc[1][1]);
      acc[1][2]=fmaf(av.y,bv.z,acc[1][2]); acc[1][3]=fmaf(av.y,bv.w,acc[1][3]);
      acc[2][0]=fmaf(av.z,bv.x,acc[2][0]); acc[2][1]=fmaf(av.z,bv.y,acc[2][1]);
      acc[2][2]=fmaf(av.z,bv.z,acc[2][2]); acc[2][3]=fmaf(av.z,bv.w,acc[2][3]);
      acc[3][0]=fmaf(av.w,bv.x,acc[3][0]); acc[3][1]=fmaf(av.w,bv.y,acc[3][1]);
      acc[3][2]=fmaf(av.w,bv.z,acc[3][2]); acc[3][3]=fmaf(av.w,bv.w,acc[3][3]);
    }
    __syncthreads();
  }
#pragma unroll
  for (int i=0;i<4;i++){
    const int r = R0 + (ty<<2) + i;
    float4 o; float* op=(float*)&o;
#pragma unroll
    for (int j=0;j<4;j++) op[j] = acc[i][j] + b4[C0 + (tx<<2) + j];
    *(float4*)&D2[r*1024 + C0 + (tx<<2)] = o;
  }
}

// ---------------- kernel A: split-K partial GEMMs + s0 update ----------------
// bid <  512 : s1 partials  (sp2 @ W3), tile=bid>>3, kchunk=bid&7
// bid < 1024 : s2 partials  (rho(s1) @ W2)
// bid >=1024 : s0 rows (sp1 @ W1, full K) -> writes s0n WITH epilogue
__global__ __launch_bounds__(256) void partial_kernel(
    const float* __restrict__ s0o, const float* __restrict__ s1o,
    const float* __restrict__ sp1, const float* __restrict__ sp2,
    const float* __restrict__ W1, const float* __restrict__ W2,
    const float* __restrict__ W3, const float* __restrict__ b0,
    float* __restrict__ P1, float* __restrict__ P2, float* __restrict__ s0n)
{
  const int bid = blockIdx.x;
  const int tid = threadIdx.x;
  if (bid < 1024){
    __shared__ float As[16][64];
    __shared__ float Bs[16][64];
    const bool m1 = bid < 512;
    const int lb = m1 ? bid : bid - 512;
    const int tb = lb >> 3;
    const int p  = lb & 7;
    const int R0 = (tb >> 4) << 6;
    const int C0 = (tb & 15) << 6;
    const int kc0 = p << 7;
    const float* __restrict__ A = m1 ? sp2 : s1o;
    const float* __restrict__ B = m1 ? W3  : W2;
    float* __restrict__ P = (m1 ? P1 : P2) + p * 262144;
    const int ty = tid >> 4, tx = tid & 15;
    const int mA = tid >> 2, kqA = (tid & 3) << 2;
    const int kB = tid >> 4, cB = (tid & 15) << 2;
    float acc[4][4] = {{0.f}};
    for (int kk = 0; kk < 128; kk += 16){
      float4 a = *(const float4*)&A[(R0+mA)*1024 + kc0 + kk + kqA];
      if (!m1){
        a.x = fminf(fmaxf(a.x,0.f),1.f); a.y = fminf(fmaxf(a.y,0.f),1.f);
        a.z = fminf(fmaxf(a.z,0.f),1.f); a.w = fminf(fmaxf(a.w,0.f),1.f);
      }
      As[kqA+0][mA]=a.x; As[kqA+1][mA]=a.y; As[kqA+2][mA]=a.z; As[kqA+3][mA]=a.w;
      *(float4*)&Bs[kB][cB] = *(const float4*)&B[(kc0+kk+kB)*1024 + C0 + cB];
      __syncthreads();
#pragma unroll
      for (int k=0;k<16;k++){
        const float4 av = *(const float4*)&As[k][ty<<2];
        const float4 bv = *(const float4*)&Bs[k][tx<<2];
        acc[0][0]=fmaf(av.x,bv.x,acc[0][0]); acc[0][1]=fmaf(av.x,bv.y,acc[0][1]);
        acc[0][2]=fmaf(av.x,bv.z,acc[0][2]); acc[0][3]=fmaf(av.x,bv.w,acc[0][3]);
        acc[1][0]=fmaf(av.y,bv.x,acc[1][0]); acc[1][1]=fmaf(av.y,bv.y,acc[1][1]);
        acc[1][2]=fmaf(av.y,bv.z,acc[1][2]); acc[1][3]=fmaf(av.y,bv.w,acc[1][3]);
        acc[2][0]=fmaf(av.z,bv.x,acc[2][0]); acc[2][1]=fmaf(av.z,bv.y,acc[2][1]);
        acc[2][2]=fmaf(av.z,bv.z,acc[2][2]); acc[2][3]=fmaf(av.z,bv.w,acc[2][3]);
        acc[3][0]=fmaf(av.w,bv.x,acc[3][0]); acc[3][1]=fmaf(av.w,bv.y,acc[3][1]);
        acc[3][2]=fmaf(av.w,bv.z,acc[3][2]); acc[3][3]=fmaf(av.w,bv.w,acc[3][3]);
      }
      __syncthreads();
    }
#pragma unroll
    for (int i=0;i<4;i++){
      const int r = R0 + (ty<<2) + i;
      float4 o; float* op=(float*)&o;
#pragma unroll
      for (int j=0;j<4;j++) op[j] = acc[i][j];
      *(float4*)&P[r*1024 + C0 + (tx<<2)] = o;
    }
  } else {
    const int r    = ((bid - 1024) << 4) + (tid >> 4);
    const int lane = tid & 15;
    float a[10] = {0.f,0.f,0.f,0.f,0.f,0.f,0.f,0.f,0.f,0.f};
    for (int k = lane; k < 1024; k += 16){
      const float sv = sp1[r*1024 + k];
#pragma unroll
      for (int c=0;c<10;c++) a[c] = fmaf(sv, W1[k*10+c], a[c]);
    }
#pragma unroll
    for (int c=0;c<10;c++){
      float v = a[c];
      v += __shfl_xor(v, 1);
      v += __shfl_xor(v, 2);
      v += __shfl_xor(v, 4);
      v += __shfl_xor(v, 8);
      a[c] = v;
    }
    if (lane == 0){
#pragma unroll
      for (int c=0;c<10;c++){
        const float s = s0o[r*10+c];
        float v = s + DTv*(-s + a[c] + b0[c]);
        s0n[r*10+c] = fminf(fmaxf(v,0.f),1.f);
      }
    }
  }
}

// ---------------- kernel B: reduce partials + epilogue + next-step spikes ----------------
// bid < 256  : s1 row r=bid   (+= b2 + sp0_old @ W1^T), write s1n + sp1_next
// bid < 512  : s2 row r=bid-256 (+= D2), write s2n + sp2_next
// bid == 512 : sp0_next from s0n
__global__ __launch_bounds__(256) void finish_kernel(
    const float* __restrict__ s1o, const float* __restrict__ s2o,
    const float* __restrict__ P1, const float* __restrict__ P2,
    const float* __restrict__ sp0_old, const float* __restrict__ s0n,
    const float* __restrict__ W1, const float* __restrict__ b2, const float* __restrict__ D2,
    float* __restrict__ s1n, float* __restrict__ s2n,
    float* __restrict__ sp0n, float* __restrict__ sp1n, float* __restrict__ sp2n,
    int tnext)
{
  __shared__ uint32_t K[6];
  if (threadIdx.x == 0) step_keys(tnext, K);
  __syncthreads();
  const int bid = blockIdx.x;
  const int tid = threadIdx.x;
  if (bid < 512){
    const bool L1 = bid < 256;
    const int r = L1 ? bid : bid - 256;
    const int c0 = tid << 2;
    const int e = (r << 10) + c0;
    const float* __restrict__ P = L1 ? P1 : P2;
    float4 acc = *(const float4*)&P[e];
#pragma unroll
    for (int p = 1; p < 8; ++p){
      const float4 q = *(const float4*)&P[p*262144 + e];
      acc.x += q.x; acc.y += q.y; acc.z += q.z; acc.w += q.w;
    }
    float val[4] = {acc.x, acc.y, acc.z, acc.w};
    if (L1){
      float sv[10];
#pragma unroll
      for (int k=0;k<10;k++) sv[k] = sp0_old[r*10+k];
      const float4 bb = *(const float4*)&b2[c0];
      const float* bp = (const float*)&bb;
#pragma unroll
      for (int j=0;j<4;j++){
        float sm = 0.f;
#pragma unroll
        for (int k=0;k<10;k++) sm = fmaf(sv[k], W1[(c0+j)*10+k], sm);
        val[j] += bp[j] + sm;
      }
    } else {
      const float4 dd = *(const float4*)&D2[e];
      val[0] += dd.x; val[1] += dd.y; val[2] += dd.z; val[3] += dd.w;
    }
    const float4 so = L1 ? *(const float4*)&s1o[e] : *(const float4*)&s2o[e];
    const float* sp_ = (const float*)&so;
    const uint32_t kk0 = L1 ? K[2] : K[4];
    const uint32_t kk1 = L1 ? K[3] : K[5];
    float4 nst, spk;
    float* np = (float*)&nst; float* kp = (float*)&spk;
#pragma unroll
    for (int j=0;j<4;j++){
      const float s = sp_[j];
      float v = s + DTv*(-s + val[j]);
      v = fminf(fmaxf(v,0.f),1.f);
      np[j] = v;
      uint32_t x0 = 0u, x1 = (uint32_t)(e + j);
      tf2x32(kk0, kk1, x0, x1);
      kp[j] = (u01(x0 ^ x1) < v) ? 1.0f : 0.0f;   // rho(v)=v, already clipped
    }
    if (L1){ *(float4*)&s1n[e] = nst; *(float4*)&sp1n[e] = spk; }
    else   { *(float4*)&s2n[e] = nst; *(float4*)&sp2n[e] = spk; }
  } else {
    for (int i = tid; i < 2560; i += 256){
      uint32_t x0 = 0u, x1 = (uint32_t)i;
      tf2x32(K[0], K[1], x0, x1);
      sp0n[i] = (u01(x0 ^ x1) < s0n[i]) ? 1.0f : 0.0f;  // s0n already clipped
    }
  }
}

// ---------------- host ----------------
extern "C" void kernel_launch(void* const* d_in, const int* in_sizes, int n_in,
                              void* d_out, int out_size, void* d_ws, size_t ws_size,
                              hipStream_t stream)
{
  const float* data = (const float*)d_in[0];
  const float* s0i  = (const float*)d_in[1];
  const float* s1i  = (const float*)d_in[2];
  const float* s2i  = (const float*)d_in[3];
  const float* b0   = (const float*)d_in[5];
  const float* W1   = (const float*)d_in[6];
  const float* W2   = (const float*)d_in[7];
  const float* b2   = (const float*)d_in[8];
  const float* W3   = (const float*)d_in[9];
  const float* W4   = (const float*)d_in[10];
  const float* b4   = (const float*)d_in[11];
  float* out = (float*)d_out;
  float* ws  = (float*)d_ws;

  // ws layout (floats), total 6,563,840 (~26.3 MB)
  const int SZ = 526848;           // 2560 + 262144 + 262144
  float* S[2][3]; float* SP[2][3];
  for (int b = 0; b < 2; ++b){
    float* sb = ws + b*SZ;
    S[b][0]=sb; S[b][1]=sb+2560; S[b][2]=sb+264704;
    float* pb = ws + 2*SZ + b*SZ;
    SP[b][0]=pb; SP[b][1]=pb+2560; SP[b][2]=pb+264704;
  }
  float* P1 = ws + 4*SZ;            // 8 * 262144
  float* P2 = P1 + 8*262144;        // 8 * 262144
  float* D2 = P2 + 8*262144;        // 262144

  init_kernel<<<1024,256,0,stream>>>(s0i,s1i,s2i,data, S[0][0],S[0][1],S[0][2], out + 526848);
  d2_kernel<<<64,256,0,stream>>>(data, W4, b4, D2);
  spike_kernel<<<2058,256,0,stream>>>(S[0][0],S[0][1],S[0][2], SP[0][0],SP[0][1],SP[0][2], 0);
  int cur = 0;
  for (int t = 0; t < 30; ++t){
    const int nxt = cur ^ 1;
    partial_kernel<<<1040,256,0,stream>>>(
        S[cur][0], S[cur][1], SP[cur][1], SP[cur][2],
        W1, W2, W3, b0, P1, P2, S[nxt][0]);
    finish_kernel<<<513,256,0,stream>>>(
        S[cur][1], S[cur][2], P1, P2, SP[cur][0], S[nxt][0],
        W1, b2, D2, S[nxt][1], S[nxt][2],
        SP[nxt][0], SP[nxt][1], SP[nxt][2], t+1);
    cur = nxt;
  }
  final_kernel<<<1024,256,0,stream>>>(S[cur][0],S[cur][1],S[cur][2], out);
}